// Round 20
// baseline (256.798 us; speedup 1.0000x reference)
//
#include <hip/hip_runtime.h>
#include <math.h>

#define NN 50000
#define NE 800000
#define ET (NE + NN)
#define FIN 256
#define HIDC 256
#define OC 64
#define NH 4
#define NEG 0.2f
#define CAP 64
#define NSTRIPES (NN / 16)            // 3125

typedef __attribute__((ext_vector_type(8))) short bf16x8;
typedef __attribute__((ext_vector_type(4))) float f32x4;

__device__ __forceinline__ unsigned short f2bf(float f) {
    unsigned u = __float_as_uint(f);
    unsigned r = (u + 0x7FFFu + ((u >> 16) & 1u)) >> 16;
    return (unsigned short)r;
}
__device__ __forceinline__ float bflo(unsigned v) { return __uint_as_float(v << 16); }
__device__ __forceinline__ float bfhi(unsigned v) { return __uint_as_float(v & 0xffff0000u); }

// ---- scatter (8 edges/thread, batched chains) ----
#define SCB 8
#define NB_SC ((ET + 256 * SCB - 1) / (256 * SCB))   // 416

__device__ __forceinline__ void scatter_body(const int* __restrict__ ei,
                                             int* __restrict__ cnt,
                                             unsigned short* __restrict__ esrc,
                                             int b, int tid) {
    int ebase = b * (256 * SCB) + tid;
    int s[SCB], d[SCB], k[SCB];
    bool v[SCB];
#pragma unroll
    for (int i = 0; i < SCB; i++) {
        int e = ebase + i * 256;
        v[i] = (e < ET);
        s[i] = 0; d[i] = 0;
        if (v[i]) {
            if (e < NE) { s[i] = ei[e]; d[i] = ei[NE + e]; }
            else { s[i] = d[i] = e - NE; }
        }
    }
#pragma unroll
    for (int i = 0; i < SCB; i++)
        if (v[i]) k[i] = atomicAdd(&cnt[d[i]], 1);
#pragma unroll
    for (int i = 0; i < SCB; i++)
        if (v[i] && k[i] < CAP) esrc[(size_t)d[i] * CAP + k[i]] = (unsigned short)s[i];
}

// ---- merged prep: cvt | pack1 | pack2 ----
#define NB_CV (NN * FIN / 8 / 256)                   // 6250
#define NB_P1 32
#define NB_P2 8

__device__ __forceinline__ void pack_body(const float* __restrict__ W,
                                          unsigned short* __restrict__ Bp,
                                          int N, int NTL, int t) {
    int lane = t & 63;
    int ntl = (t >> 6) % NTL;
    int ks = ((t >> 6) / NTL) & 7;
    int hy = t / (64 * NTL * 8);
    int col = hy * NTL * 16 + ntl * 16 + (lane & 15);
    int k0 = ks * 32 + (lane >> 4) * 8;
#pragma unroll
    for (int i = 0; i < 8; i++) Bp[(size_t)t * 8 + i] = f2bf(W[(k0 + i) * N + col]);
}

__global__ void k_prep(const float* __restrict__ x, unsigned short* __restrict__ xb,
                       const float* __restrict__ W1, unsigned short* __restrict__ Bp1,
                       const float* __restrict__ W2, unsigned short* __restrict__ Bp2) {
    int b = blockIdx.x, tid = threadIdx.x;
    if (b < NB_CV) {
        int i = (b * 256 + tid) * 8;
        float4 f0 = *(const float4*)&x[i];
        float4 f1 = *(const float4*)&x[i + 4];
        uint4 o;
        o.x = (unsigned)f2bf(f0.x) | ((unsigned)f2bf(f0.y) << 16);
        o.y = (unsigned)f2bf(f0.z) | ((unsigned)f2bf(f0.w) << 16);
        o.z = (unsigned)f2bf(f1.x) | ((unsigned)f2bf(f1.y) << 16);
        o.w = (unsigned)f2bf(f1.z) | ((unsigned)f2bf(f1.w) << 16);
        *(uint4*)&xb[i] = o;
    } else if (b < NB_CV + NB_P1) {
        pack_body(W1, Bp1, HIDC, 8, (b - NB_CV) * 256 + tid);
    } else {
        pack_body(W2, Bp2, OC, 4, (b - NB_CV - NB_P1) * 256 + tid);
    }
}

// ---- bf16 MFMA GEMM, MR=1 (low VGPR -> 3 waves/SIMD), no LDS for B,
//      LDS-transposed coalesced D-store, fused per-head alpha.
//      SCAT: scatter plane at blockIdx.y==0 (dispatched first, overlaps GEMM). ----
template <int NTL, int NHEADS, bool SCAT>
__global__ void __launch_bounds__(256, 3) k_gemm(const unsigned short* __restrict__ A,
                                              const unsigned short* __restrict__ Bp,
                                              unsigned short* __restrict__ D, int N,
                                              const float* __restrict__ aS,
                                              const float* __restrict__ aD,
                                              float* __restrict__ asOut,
                                              float* __restrict__ adOut,
                                              const int* __restrict__ ei,
                                              int* __restrict__ cnt,
                                              unsigned short* __restrict__ esrc) {
    constexpr int TOT = 8 * NTL * 64 * 8;
    constexpr int HPH = (NTL * 16) / 64;
    constexpr int CH = NTL * 16;  // cols per half
    __shared__ unsigned short sd[4][16][CH];
    if (SCAT && blockIdx.y == 0) {
        scatter_body(ei, cnt, esrc, blockIdx.x, threadIdx.x);
        return;
    }
    int yb = SCAT ? (int)blockIdx.y - 1 : (int)blockIdx.y;
    const unsigned short* bsrc = Bp + (size_t)yb * TOT;
    int wave = threadIdx.x >> 6, lane = threadIdx.x & 63;
    int l15 = lane & 15, lh = lane >> 4;
    int coloff = yb * CH;
    float aSv[NTL], aDv[NTL];
#pragma unroll
    for (int nt = 0; nt < NTL; nt++) {
        aSv[nt] = aS[coloff + nt * 16 + l15];
        aDv[nt] = aD[coloff + nt * 16 + l15];
    }
    for (int st = blockIdx.x * 4 + wave; st < NSTRIPES; st += gridDim.x * 4) {
        const unsigned short* arow = A + (size_t)(st * 16 + l15) * 256 + lh * 8;
        bf16x8 a[8];
#pragma unroll
        for (int ks = 0; ks < 8; ks++) a[ks] = *(const bf16x8*)(arow + ks * 32);
        f32x4 acc[NTL];
#pragma unroll
        for (int t = 0; t < NTL; t++) acc[t] = (f32x4){0.f, 0.f, 0.f, 0.f};
#pragma unroll
        for (int ks = 0; ks < 8; ks++) {
#pragma unroll
            for (int nt = 0; nt < NTL; nt++) {
                bf16x8 b = *(const bf16x8*)&bsrc[((size_t)(ks * NTL + nt) * 64 + lane) * 8];
                acc[nt] = __builtin_amdgcn_mfma_f32_16x16x32_bf16(a[ks], b, acc[nt], 0, 0, 0);
            }
        }
        int strow = st * 16;
        // stage fragment-order -> LDS (wave-local, no barrier)
#pragma unroll
        for (int nt = 0; nt < NTL; nt++)
#pragma unroll
            for (int r = 0; r < 4; r++)
                sd[wave][lh * 4 + r][nt * 16 + l15] = f2bf(acc[nt][r]);
        // coalesced store: 4 lanes per row, uint4 (16B) each
        unsigned short* dbase = D + (size_t)strow * N + coloff;
        int row = lane >> 2, q = lane & 3;
#pragma unroll
        for (int it = 0; it < NTL / 2; it++) {
            int c8 = it * 4 + q;
            uint4 v = *(const uint4*)&sd[wave][row][c8 * 8];
            *(uint4*)&dbase[(size_t)row * N + c8 * 8] = v;
        }
        // fused per-head alpha dots
#pragma unroll
        for (int r = 0; r < 4; r++) {
#pragma unroll
            for (int gg = 0; gg < HPH; gg++) {
                float ps = 0.f, pd = 0.f;
#pragma unroll
                for (int q2 = 0; q2 < 4; q2++) {
                    int nt = gg * 4 + q2;
                    ps += acc[nt][r] * aSv[nt];
                    pd += acc[nt][r] * aDv[nt];
                }
#pragma unroll
                for (int off = 1; off < 16; off <<= 1) {
                    ps += __shfl_xor(ps, off);
                    pd += __shfl_xor(pd, off);
                }
                if (l15 == 0) {
                    int rowi = strow + lh * 4 + r;
                    int hidx = yb * HPH + gg;
                    asOut[rowi * NHEADS + hidx] = ps;
                    adOut[rowi * NHEADS + hidx] = pd;
                }
            }
        }
    }
}

// ============ fused attention+aggregation: wave per node ============
__global__ void k_agg1f(const int* __restrict__ cnt, const unsigned short* __restrict__ esrc,
                        const unsigned short* __restrict__ h, const float* __restrict__ as,
                        const float* __restrict__ ad, const float* __restrict__ bias,
                        unsigned short* __restrict__ out) {
    __shared__ float wlds[4][64][4];
    int wave = threadIdx.x >> 6;
    int n = blockIdx.x * 4 + wave;
    int lane = threadIdx.x & 63;
    if (n >= NN) return;
    int deg = cnt[n];
    deg = deg < CAP ? deg : CAP;
    const unsigned short* bucket = &esrc[(size_t)n * CAP];
    bool act = lane < deg;
    int myS = act ? (int)bucket[lane] : 0;
    float4 adv = *(const float4*)&ad[n * NH];
    float e0 = -INFINITY, e1 = -INFINITY, e2 = -INFINITY, e3 = -INFINITY;
    if (act) {
        float4 av = *(const float4*)&as[myS * NH];
        e0 = av.x + adv.x; e0 = e0 > 0.f ? e0 : NEG * e0;
        e1 = av.y + adv.y; e1 = e1 > 0.f ? e1 : NEG * e1;
        e2 = av.z + adv.z; e2 = e2 > 0.f ? e2 : NEG * e2;
        e3 = av.w + adv.w; e3 = e3 > 0.f ? e3 : NEG * e3;
    }
    float m0 = e0, m1 = e1, m2 = e2, m3 = e3;
    for (int off = 32; off; off >>= 1) {
        m0 = fmaxf(m0, __shfl_xor(m0, off));
        m1 = fmaxf(m1, __shfl_xor(m1, off));
        m2 = fmaxf(m2, __shfl_xor(m2, off));
        m3 = fmaxf(m3, __shfl_xor(m3, off));
    }
    float w0 = act ? expf(e0 - m0) : 0.f;
    float w1 = act ? expf(e1 - m1) : 0.f;
    float w2 = act ? expf(e2 - m2) : 0.f;
    float w3 = act ? expf(e3 - m3) : 0.f;
    *(float4*)&wlds[wave][lane][0] = (float4){w0, w1, w2, w3};
    float s0 = w0, s1 = w1, s2 = w2, s3 = w3;
    for (int off = 32; off; off >>= 1) {
        s0 += __shfl_xor(s0, off);
        s1 += __shfl_xor(s1, off);
        s2 += __shfl_xor(s2, off);
        s3 += __shfl_xor(s3, off);
    }
    int hh = lane >> 4;
    int cbase = hh * 64 + (lane & 15) * 4;
    float ssel = hh == 0 ? s0 : hh == 1 ? s1 : hh == 2 ? s2 : s3;
    float rsel = 1.f / (ssel + 1e-16f);
    const float* wcol = &wlds[wave][0][hh];
    const unsigned short* hb = h + cbase;
    float acc0 = 0.f, acc1 = 0.f, acc2 = 0.f, acc3 = 0.f;
    int degP = (deg + 7) & ~7;
    for (int j = 0; j < degP; j += 8) {
        uint2 pv[8];
        float wj[8];
#pragma unroll
        for (int u = 0; u < 8; u++) {
            int s = __shfl(myS, j + u);
            wj[u] = wcol[(j + u) * 4];
            pv[u] = *(const uint2*)&hb[(size_t)s * HIDC];
        }
#pragma unroll
        for (int u = 0; u < 8; u++) {
            acc0 += wj[u] * bflo(pv[u].x);
            acc1 += wj[u] * bfhi(pv[u].x);
            acc2 += wj[u] * bflo(pv[u].y);
            acc3 += wj[u] * bfhi(pv[u].y);
        }
    }
    float4 bv = *(const float4*)&bias[cbase];
    float v0 = acc0 * rsel + bv.x; v0 = v0 > 0.f ? v0 : expm1f(v0);
    float v1 = acc1 * rsel + bv.y; v1 = v1 > 0.f ? v1 : expm1f(v1);
    float v2 = acc2 * rsel + bv.z; v2 = v2 > 0.f ? v2 : expm1f(v2);
    float v3 = acc3 * rsel + bv.w; v3 = v3 > 0.f ? v3 : expm1f(v3);
    uint2 ov;
    ov.x = (unsigned)f2bf(v0) | ((unsigned)f2bf(v1) << 16);
    ov.y = (unsigned)f2bf(v2) | ((unsigned)f2bf(v3) << 16);
    *(uint2*)&out[(size_t)n * HIDC + cbase] = ov;
}

// layer2: 8 edges per iteration
__global__ void k_agg2f(const int* __restrict__ cnt, const unsigned short* __restrict__ esrc,
                        const unsigned short* __restrict__ h, const float* __restrict__ as,
                        const float* __restrict__ ad, const float* __restrict__ bias,
                        float* __restrict__ out) {
    __shared__ float wlds[4][64];
    int wave = threadIdx.x >> 6;
    int n = blockIdx.x * 4 + wave;
    int lane = threadIdx.x & 63;
    if (n >= NN) return;
    int deg = cnt[n];
    deg = deg < CAP ? deg : CAP;
    const unsigned short* bucket = &esrc[(size_t)n * CAP];
    bool act = lane < deg;
    int myS = act ? (int)bucket[lane] : 0;
    float adv = ad[n];
    float e = -INFINITY;
    if (act) {
        e = as[myS] + adv;
        e = e > 0.f ? e : NEG * e;
    }
    float m = e;
    for (int off = 32; off; off >>= 1) m = fmaxf(m, __shfl_xor(m, off));
    float w = act ? expf(e - m) : 0.f;
    wlds[wave][lane] = w;
    float s = w;
    for (int off = 32; off; off >>= 1) s += __shfl_xor(s, off);
    float rd = 1.f / (s + 1e-16f);

    int sub = lane >> 4;
    int cw = (lane & 15) * 4;
    const unsigned short* hb = h + cw;
    float acc0 = 0.f, acc1 = 0.f, acc2 = 0.f, acc3 = 0.f;
    int degP = (deg + 7) & ~7;
    for (int j = 0; j < degP; j += 8) {
        uint2 pv[2];
        float wj[2];
#pragma unroll
        for (int u = 0; u < 2; u++) {
            int jj = j + u * 4 + sub;
            int sj = __shfl(myS, jj);
            wj[u] = wlds[wave][jj];
            pv[u] = *(const uint2*)&hb[(size_t)sj * OC];
        }
#pragma unroll
        for (int u = 0; u < 2; u++) {
            acc0 += wj[u] * bflo(pv[u].x);
            acc1 += wj[u] * bfhi(pv[u].x);
            acc2 += wj[u] * bflo(pv[u].y);
            acc3 += wj[u] * bfhi(pv[u].y);
        }
    }
#pragma unroll
    for (int off = 16; off < 64; off <<= 1) {
        acc0 += __shfl_xor(acc0, off);
        acc1 += __shfl_xor(acc1, off);
        acc2 += __shfl_xor(acc2, off);
        acc3 += __shfl_xor(acc3, off);
    }
    if (lane < 16) {
        float4 bv = *(const float4*)&bias[cw];
        float4 o;
        o.x = acc0 * rd + bv.x;
        o.y = acc1 * rd + bv.y;
        o.z = acc2 * rd + bv.z;
        o.w = acc3 * rd + bv.w;
        *(float4*)&out[(size_t)n * OC + cw] = o;
    }
}

extern "C" void kernel_launch(void* const* d_in, const int* in_sizes, int n_in,
                              void* d_out, int out_size, void* d_ws, size_t ws_size,
                              hipStream_t stream) {
    const float* x   = (const float*)d_in[0];
    const int*   ei  = (const int*)d_in[1];
    const float* W1  = (const float*)d_in[2];
    const float* aS1 = (const float*)d_in[3];
    const float* aD1 = (const float*)d_in[4];
    const float* b1  = (const float*)d_in[5];
    const float* W2  = (const float*)d_in[6];
    const float* aS2 = (const float*)d_in[7];
    const float* aD2 = (const float*)d_in[8];
    const float* b2  = (const float*)d_in[9];
    float* out = (float*)d_out;

    char* p = (char*)d_ws;
    auto alloc = [&](size_t nbytes) {
        char* r = p;
        p += (nbytes + 255) & ~(size_t)255;
        return r;
    };
    unsigned short* xb    = (unsigned short*)alloc((size_t)NN * FIN * 2);
    unsigned short* h1b   = (unsigned short*)alloc((size_t)NN * HIDC * 2);
    unsigned short* act1b = (unsigned short*)alloc((size_t)NN * HIDC * 2);
    unsigned short* h2b   = (unsigned short*)alloc((size_t)NN * OC * 2);
    unsigned short* Bp1   = (unsigned short*)alloc((size_t)2 * 8 * 8 * 64 * 8 * 2);
    unsigned short* Bp2   = (unsigned short*)alloc((size_t)1 * 8 * 4 * 64 * 8 * 2);
    float* as1  = (float*)alloc((size_t)NN * NH * 4);
    float* ad1  = (float*)alloc((size_t)NN * NH * 4);
    float* as2  = (float*)alloc((size_t)NN * 4);
    float* ad2  = (float*)alloc((size_t)NN * 4);
    int*   cnt  = (int*)alloc((size_t)NN * 4);
    unsigned short* esrc = (unsigned short*)alloc((size_t)NN * CAP * 2);

    hipMemsetAsync(cnt, 0, (size_t)NN * 4, stream);

    // ---- prep: cvt + weight packing ----
    k_prep<<<NB_CV + NB_P1 + NB_P2, 256, 0, stream>>>(x, xb, W1, Bp1, W2, Bp2);

    // ---- layer 1: scatter plane (y==0) + GEMM planes (y=1,2) ----
    k_gemm<8, NH, true><<<dim3(NB_SC, 3), 256, 0, stream>>>(xb, Bp1, h1b, HIDC,
                                                            aS1, aD1, as1, ad1,
                                                            ei, cnt, esrc);
    k_agg1f<<<(NN + 3) / 4, 256, 0, stream>>>(cnt, esrc, h1b, as1, ad1, b1, act1b);

    // ---- layer 2 ----
    k_gemm<4, 1, false><<<dim3(391, 1), 256, 0, stream>>>(act1b, Bp2, h2b, OC,
                                                          aS2, aD2, as2, ad2,
                                                          nullptr, nullptr, nullptr);
    k_agg2f<<<(NN + 3) / 4, 256, 0, stream>>>(cnt, esrc, h2b, as2, ad2, b2, out);
}

// Round 21
// 194.510 us; speedup vs baseline: 1.3202x; 1.3202x over previous
//
#include <hip/hip_runtime.h>
#include <math.h>

#define NN 50000
#define NE 800000
#define ET (NE + NN)
#define FIN 256
#define HIDC 256
#define OC 64
#define NH 4
#define NEG 0.2f
#define CAP 64
#define NSTRIPES (NN / 16)            // 3125

typedef __attribute__((ext_vector_type(8))) short bf16x8;
typedef __attribute__((ext_vector_type(4))) float f32x4;

__device__ __forceinline__ unsigned short f2bf(float f) {
    unsigned u = __float_as_uint(f);
    unsigned r = (u + 0x7FFFu + ((u >> 16) & 1u)) >> 16;
    return (unsigned short)r;
}
__device__ __forceinline__ float bflo(unsigned v) { return __uint_as_float(v << 16); }
__device__ __forceinline__ float bfhi(unsigned v) { return __uint_as_float(v & 0xffff0000u); }

// ---- scatter (8 edges/thread, batched chains) ----
#define SCB 8
#define NB_SC ((ET + 256 * SCB - 1) / (256 * SCB))   // 416

__device__ __forceinline__ void scatter_body(const int* __restrict__ ei,
                                             int* __restrict__ cnt,
                                             unsigned short* __restrict__ esrc,
                                             int b, int tid) {
    int ebase = b * (256 * SCB) + tid;
    int s[SCB], d[SCB], k[SCB];
    bool v[SCB];
#pragma unroll
    for (int i = 0; i < SCB; i++) {
        int e = ebase + i * 256;
        v[i] = (e < ET);
        s[i] = 0; d[i] = 0;
        if (v[i]) {
            if (e < NE) { s[i] = ei[e]; d[i] = ei[NE + e]; }
            else { s[i] = d[i] = e - NE; }
        }
    }
#pragma unroll
    for (int i = 0; i < SCB; i++)
        if (v[i]) k[i] = atomicAdd(&cnt[d[i]], 1);
#pragma unroll
    for (int i = 0; i < SCB; i++)
        if (v[i] && k[i] < CAP) esrc[(size_t)d[i] * CAP + k[i]] = (unsigned short)s[i];
}

// ---- merged prep: cvt | pack1 | pack2 ----
#define NB_CV (NN * FIN / 8 / 256)                   // 6250
#define NB_P1 32
#define NB_P2 8

__device__ __forceinline__ void pack_body(const float* __restrict__ W,
                                          unsigned short* __restrict__ Bp,
                                          int N, int NTL, int t) {
    int lane = t & 63;
    int ntl = (t >> 6) % NTL;
    int ks = ((t >> 6) / NTL) & 7;
    int hy = t / (64 * NTL * 8);
    int col = hy * NTL * 16 + ntl * 16 + (lane & 15);
    int k0 = ks * 32 + (lane >> 4) * 8;
#pragma unroll
    for (int i = 0; i < 8; i++) Bp[(size_t)t * 8 + i] = f2bf(W[(k0 + i) * N + col]);
}

__global__ void k_prep(const float* __restrict__ x, unsigned short* __restrict__ xb,
                       const float* __restrict__ W1, unsigned short* __restrict__ Bp1,
                       const float* __restrict__ W2, unsigned short* __restrict__ Bp2) {
    int b = blockIdx.x, tid = threadIdx.x;
    if (b < NB_CV) {
        int i = (b * 256 + tid) * 8;
        float4 f0 = *(const float4*)&x[i];
        float4 f1 = *(const float4*)&x[i + 4];
        uint4 o;
        o.x = (unsigned)f2bf(f0.x) | ((unsigned)f2bf(f0.y) << 16);
        o.y = (unsigned)f2bf(f0.z) | ((unsigned)f2bf(f0.w) << 16);
        o.z = (unsigned)f2bf(f1.x) | ((unsigned)f2bf(f1.y) << 16);
        o.w = (unsigned)f2bf(f1.z) | ((unsigned)f2bf(f1.w) << 16);
        *(uint4*)&xb[i] = o;
    } else if (b < NB_CV + NB_P1) {
        pack_body(W1, Bp1, HIDC, 8, (b - NB_CV) * 256 + tid);
    } else {
        pack_body(W2, Bp2, OC, 4, (b - NB_CV - NB_P1) * 256 + tid);
    }
}

// ---- bf16 MFMA GEMM, MR=1 (natural VGPR ~120 -> 3-4 waves/SIMD, NO forced cap),
//      no LDS for B, LDS-transposed coalesced D-store, fused per-head alpha.
//      SCAT: scatter plane at blockIdx.y==0 (dispatched first, overlaps GEMM). ----
template <int NTL, int NHEADS, bool SCAT>
__global__ void __launch_bounds__(256) k_gemm(const unsigned short* __restrict__ A,
                                              const unsigned short* __restrict__ Bp,
                                              unsigned short* __restrict__ D, int N,
                                              const float* __restrict__ aS,
                                              const float* __restrict__ aD,
                                              float* __restrict__ asOut,
                                              float* __restrict__ adOut,
                                              const int* __restrict__ ei,
                                              int* __restrict__ cnt,
                                              unsigned short* __restrict__ esrc) {
    constexpr int TOT = 8 * NTL * 64 * 8;
    constexpr int HPH = (NTL * 16) / 64;
    constexpr int CH = NTL * 16;  // cols per half
    __shared__ unsigned short sd[4][16][CH];
    if (SCAT && blockIdx.y == 0) {
        scatter_body(ei, cnt, esrc, blockIdx.x, threadIdx.x);
        return;
    }
    int yb = SCAT ? (int)blockIdx.y - 1 : (int)blockIdx.y;
    const unsigned short* bsrc = Bp + (size_t)yb * TOT;
    int wave = threadIdx.x >> 6, lane = threadIdx.x & 63;
    int l15 = lane & 15, lh = lane >> 4;
    int coloff = yb * CH;
    float aSv[NTL], aDv[NTL];
#pragma unroll
    for (int nt = 0; nt < NTL; nt++) {
        aSv[nt] = aS[coloff + nt * 16 + l15];
        aDv[nt] = aD[coloff + nt * 16 + l15];
    }
    for (int st = blockIdx.x * 4 + wave; st < NSTRIPES; st += gridDim.x * 4) {
        const unsigned short* arow = A + (size_t)(st * 16 + l15) * 256 + lh * 8;
        bf16x8 a[8];
#pragma unroll
        for (int ks = 0; ks < 8; ks++) a[ks] = *(const bf16x8*)(arow + ks * 32);
        f32x4 acc[NTL];
#pragma unroll
        for (int t = 0; t < NTL; t++) acc[t] = (f32x4){0.f, 0.f, 0.f, 0.f};
#pragma unroll
        for (int ks = 0; ks < 8; ks++) {
#pragma unroll
            for (int nt = 0; nt < NTL; nt++) {
                bf16x8 b = *(const bf16x8*)&bsrc[((size_t)(ks * NTL + nt) * 64 + lane) * 8];
                acc[nt] = __builtin_amdgcn_mfma_f32_16x16x32_bf16(a[ks], b, acc[nt], 0, 0, 0);
            }
        }
        int strow = st * 16;
        // stage fragment-order -> LDS (wave-local, no barrier)
#pragma unroll
        for (int nt = 0; nt < NTL; nt++)
#pragma unroll
            for (int r = 0; r < 4; r++)
                sd[wave][lh * 4 + r][nt * 16 + l15] = f2bf(acc[nt][r]);
        // coalesced store: 4 lanes per row, uint4 (16B) each
        unsigned short* dbase = D + (size_t)strow * N + coloff;
        int row = lane >> 2, q = lane & 3;
#pragma unroll
        for (int it = 0; it < NTL / 2; it++) {
            int c8 = it * 4 + q;
            uint4 v = *(const uint4*)&sd[wave][row][c8 * 8];
            *(uint4*)&dbase[(size_t)row * N + c8 * 8] = v;
        }
        // fused per-head alpha dots
#pragma unroll
        for (int r = 0; r < 4; r++) {
#pragma unroll
            for (int gg = 0; gg < HPH; gg++) {
                float ps = 0.f, pd = 0.f;
#pragma unroll
                for (int q2 = 0; q2 < 4; q2++) {
                    int nt = gg * 4 + q2;
                    ps += acc[nt][r] * aSv[nt];
                    pd += acc[nt][r] * aDv[nt];
                }
#pragma unroll
                for (int off = 1; off < 16; off <<= 1) {
                    ps += __shfl_xor(ps, off);
                    pd += __shfl_xor(pd, off);
                }
                if (l15 == 0) {
                    int rowi = strow + lh * 4 + r;
                    int hidx = yb * HPH + gg;
                    asOut[rowi * NHEADS + hidx] = ps;
                    adOut[rowi * NHEADS + hidx] = pd;
                }
            }
        }
    }
}

// ============ fused attention+aggregation: wave per node ============
__global__ void k_agg1f(const int* __restrict__ cnt, const unsigned short* __restrict__ esrc,
                        const unsigned short* __restrict__ h, const float* __restrict__ as,
                        const float* __restrict__ ad, const float* __restrict__ bias,
                        unsigned short* __restrict__ out) {
    __shared__ float wlds[4][64][4];
    int wave = threadIdx.x >> 6;
    int n = blockIdx.x * 4 + wave;
    int lane = threadIdx.x & 63;
    if (n >= NN) return;
    int deg = cnt[n];
    deg = deg < CAP ? deg : CAP;
    const unsigned short* bucket = &esrc[(size_t)n * CAP];
    bool act = lane < deg;
    int myS = act ? (int)bucket[lane] : 0;
    float4 adv = *(const float4*)&ad[n * NH];
    float e0 = -INFINITY, e1 = -INFINITY, e2 = -INFINITY, e3 = -INFINITY;
    if (act) {
        float4 av = *(const float4*)&as[myS * NH];
        e0 = av.x + adv.x; e0 = e0 > 0.f ? e0 : NEG * e0;
        e1 = av.y + adv.y; e1 = e1 > 0.f ? e1 : NEG * e1;
        e2 = av.z + adv.z; e2 = e2 > 0.f ? e2 : NEG * e2;
        e3 = av.w + adv.w; e3 = e3 > 0.f ? e3 : NEG * e3;
    }
    float m0 = e0, m1 = e1, m2 = e2, m3 = e3;
    for (int off = 32; off; off >>= 1) {
        m0 = fmaxf(m0, __shfl_xor(m0, off));
        m1 = fmaxf(m1, __shfl_xor(m1, off));
        m2 = fmaxf(m2, __shfl_xor(m2, off));
        m3 = fmaxf(m3, __shfl_xor(m3, off));
    }
    float w0 = act ? expf(e0 - m0) : 0.f;
    float w1 = act ? expf(e1 - m1) : 0.f;
    float w2 = act ? expf(e2 - m2) : 0.f;
    float w3 = act ? expf(e3 - m3) : 0.f;
    *(float4*)&wlds[wave][lane][0] = (float4){w0, w1, w2, w3};
    float s0 = w0, s1 = w1, s2 = w2, s3 = w3;
    for (int off = 32; off; off >>= 1) {
        s0 += __shfl_xor(s0, off);
        s1 += __shfl_xor(s1, off);
        s2 += __shfl_xor(s2, off);
        s3 += __shfl_xor(s3, off);
    }
    int hh = lane >> 4;
    int cbase = hh * 64 + (lane & 15) * 4;
    float ssel = hh == 0 ? s0 : hh == 1 ? s1 : hh == 2 ? s2 : s3;
    float rsel = 1.f / (ssel + 1e-16f);
    const float* wcol = &wlds[wave][0][hh];
    const unsigned short* hb = h + cbase;
    float acc0 = 0.f, acc1 = 0.f, acc2 = 0.f, acc3 = 0.f;
    int degP = (deg + 7) & ~7;
    for (int j = 0; j < degP; j += 8) {
        uint2 pv[8];
        float wj[8];
#pragma unroll
        for (int u = 0; u < 8; u++) {
            int s = __shfl(myS, j + u);
            wj[u] = wcol[(j + u) * 4];
            pv[u] = *(const uint2*)&hb[(size_t)s * HIDC];
        }
#pragma unroll
        for (int u = 0; u < 8; u++) {
            acc0 += wj[u] * bflo(pv[u].x);
            acc1 += wj[u] * bfhi(pv[u].x);
            acc2 += wj[u] * bflo(pv[u].y);
            acc3 += wj[u] * bfhi(pv[u].y);
        }
    }
    float4 bv = *(const float4*)&bias[cbase];
    float v0 = acc0 * rsel + bv.x; v0 = v0 > 0.f ? v0 : expm1f(v0);
    float v1 = acc1 * rsel + bv.y; v1 = v1 > 0.f ? v1 : expm1f(v1);
    float v2 = acc2 * rsel + bv.z; v2 = v2 > 0.f ? v2 : expm1f(v2);
    float v3 = acc3 * rsel + bv.w; v3 = v3 > 0.f ? v3 : expm1f(v3);
    uint2 ov;
    ov.x = (unsigned)f2bf(v0) | ((unsigned)f2bf(v1) << 16);
    ov.y = (unsigned)f2bf(v2) | ((unsigned)f2bf(v3) << 16);
    *(uint2*)&out[(size_t)n * HIDC + cbase] = ov;
}

// layer2: 8 edges per iteration
__global__ void k_agg2f(const int* __restrict__ cnt, const unsigned short* __restrict__ esrc,
                        const unsigned short* __restrict__ h, const float* __restrict__ as,
                        const float* __restrict__ ad, const float* __restrict__ bias,
                        float* __restrict__ out) {
    __shared__ float wlds[4][64];
    int wave = threadIdx.x >> 6;
    int n = blockIdx.x * 4 + wave;
    int lane = threadIdx.x & 63;
    if (n >= NN) return;
    int deg = cnt[n];
    deg = deg < CAP ? deg : CAP;
    const unsigned short* bucket = &esrc[(size_t)n * CAP];
    bool act = lane < deg;
    int myS = act ? (int)bucket[lane] : 0;
    float adv = ad[n];
    float e = -INFINITY;
    if (act) {
        e = as[myS] + adv;
        e = e > 0.f ? e : NEG * e;
    }
    float m = e;
    for (int off = 32; off; off >>= 1) m = fmaxf(m, __shfl_xor(m, off));
    float w = act ? expf(e - m) : 0.f;
    wlds[wave][lane] = w;
    float s = w;
    for (int off = 32; off; off >>= 1) s += __shfl_xor(s, off);
    float rd = 1.f / (s + 1e-16f);

    int sub = lane >> 4;
    int cw = (lane & 15) * 4;
    const unsigned short* hb = h + cw;
    float acc0 = 0.f, acc1 = 0.f, acc2 = 0.f, acc3 = 0.f;
    int degP = (deg + 7) & ~7;
    for (int j = 0; j < degP; j += 8) {
        uint2 pv[2];
        float wj[2];
#pragma unroll
        for (int u = 0; u < 2; u++) {
            int jj = j + u * 4 + sub;
            int sj = __shfl(myS, jj);
            wj[u] = wlds[wave][jj];
            pv[u] = *(const uint2*)&hb[(size_t)sj * OC];
        }
#pragma unroll
        for (int u = 0; u < 2; u++) {
            acc0 += wj[u] * bflo(pv[u].x);
            acc1 += wj[u] * bfhi(pv[u].x);
            acc2 += wj[u] * bflo(pv[u].y);
            acc3 += wj[u] * bfhi(pv[u].y);
        }
    }
#pragma unroll
    for (int off = 16; off < 64; off <<= 1) {
        acc0 += __shfl_xor(acc0, off);
        acc1 += __shfl_xor(acc1, off);
        acc2 += __shfl_xor(acc2, off);
        acc3 += __shfl_xor(acc3, off);
    }
    if (lane < 16) {
        float4 bv = *(const float4*)&bias[cw];
        float4 o;
        o.x = acc0 * rd + bv.x;
        o.y = acc1 * rd + bv.y;
        o.z = acc2 * rd + bv.z;
        o.w = acc3 * rd + bv.w;
        *(float4*)&out[(size_t)n * OC + cw] = o;
    }
}

extern "C" void kernel_launch(void* const* d_in, const int* in_sizes, int n_in,
                              void* d_out, int out_size, void* d_ws, size_t ws_size,
                              hipStream_t stream) {
    const float* x   = (const float*)d_in[0];
    const int*   ei  = (const int*)d_in[1];
    const float* W1  = (const float*)d_in[2];
    const float* aS1 = (const float*)d_in[3];
    const float* aD1 = (const float*)d_in[4];
    const float* b1  = (const float*)d_in[5];
    const float* W2  = (const float*)d_in[6];
    const float* aS2 = (const float*)d_in[7];
    const float* aD2 = (const float*)d_in[8];
    const float* b2  = (const float*)d_in[9];
    float* out = (float*)d_out;

    char* p = (char*)d_ws;
    auto alloc = [&](size_t nbytes) {
        char* r = p;
        p += (nbytes + 255) & ~(size_t)255;
        return r;
    };
    unsigned short* xb    = (unsigned short*)alloc((size_t)NN * FIN * 2);
    unsigned short* h1b   = (unsigned short*)alloc((size_t)NN * HIDC * 2);
    unsigned short* act1b = (unsigned short*)alloc((size_t)NN * HIDC * 2);
    unsigned short* h2b   = (unsigned short*)alloc((size_t)NN * OC * 2);
    unsigned short* Bp1   = (unsigned short*)alloc((size_t)2 * 8 * 8 * 64 * 8 * 2);
    unsigned short* Bp2   = (unsigned short*)alloc((size_t)1 * 8 * 4 * 64 * 8 * 2);
    float* as1  = (float*)alloc((size_t)NN * NH * 4);
    float* ad1  = (float*)alloc((size_t)NN * NH * 4);
    float* as2  = (float*)alloc((size_t)NN * 4);
    float* ad2  = (float*)alloc((size_t)NN * 4);
    int*   cnt  = (int*)alloc((size_t)NN * 4);
    unsigned short* esrc = (unsigned short*)alloc((size_t)NN * CAP * 2);

    hipMemsetAsync(cnt, 0, (size_t)NN * 4, stream);

    // ---- prep: cvt + weight packing ----
    k_prep<<<NB_CV + NB_P1 + NB_P2, 256, 0, stream>>>(x, xb, W1, Bp1, W2, Bp2);

    // ---- layer 1: scatter plane (y==0) + GEMM planes (y=1,2) ----
    k_gemm<8, NH, true><<<dim3(NB_SC, 3), 256, 0, stream>>>(xb, Bp1, h1b, HIDC,
                                                            aS1, aD1, as1, ad1,
                                                            ei, cnt, esrc);
    k_agg1f<<<(NN + 3) / 4, 256, 0, stream>>>(cnt, esrc, h1b, as1, ad1, b1, act1b);

    // ---- layer 2 ----
    k_gemm<4, 1, false><<<dim3(391, 1), 256, 0, stream>>>(act1b, Bp2, h2b, OC,
                                                          aS2, aD2, as2, ad2,
                                                          nullptr, nullptr, nullptr);
    k_agg2f<<<(NN + 3) / 4, 256, 0, stream>>>(cnt, esrc, h2b, as2, ad2, b2, out);
}